// Round 1
// baseline (1448.337 us; speedup 1.0000x reference)
//
#include <hip/hip_runtime.h>
#include <stdint.h>

// Problem constants (from reference)
#define NN 100000      // nodes
#define NE 1600000     // edges per set
#define ETOT (NE + NN) // edges + self loops

typedef __attribute__((ext_vector_type(8))) short bf16x8;
typedef __attribute__((ext_vector_type(4))) float f32x4;

__device__ __forceinline__ float bf2f(unsigned short u) {
    union { unsigned int i; float f; } x; x.i = ((unsigned int)u) << 16; return x.f;
}
__device__ __forceinline__ unsigned short f2bf(float f) {
    union { float f; unsigned int i; } x; x.f = f;
    unsigned int i = x.i;
    return (unsigned short)((i + 0x7FFFu + ((i >> 16) & 1u)) >> 16);
}

// ---------- CSR build ----------
__global__ void k_init_deg(int* deg0, int* deg1) {
    int i = blockIdx.x * 256 + threadIdx.x;
    if (i < NN) { deg0[i] = 1; deg1[i] = 1; }   // self-loop included
}

__global__ void k_count(const int* col, int* deg) {
    int e = blockIdx.x * 256 + threadIdx.x;
    if (e < NE) atomicAdd(&deg[col[e]], 1);
}

// block scans 1024 elems (4/thread); writes inclusive scan into rowptr[i+1]
__global__ void k_scan1(const int* deg, int* rp1, int* bsum) {
    __shared__ int s[256];
    int tid = threadIdx.x;
    int base = blockIdx.x * 1024 + tid * 4;
    int v0 = 0, v1 = 0, v2 = 0, v3 = 0;
    if (base + 0 < NN) v0 = deg[base + 0];
    if (base + 1 < NN) v1 = deg[base + 1];
    if (base + 2 < NN) v2 = deg[base + 2];
    if (base + 3 < NN) v3 = deg[base + 3];
    int sum = v0 + v1 + v2 + v3;
    s[tid] = sum; __syncthreads();
    for (int off = 1; off < 256; off <<= 1) {
        int t = (tid >= off) ? s[tid - off] : 0;
        __syncthreads(); s[tid] += t; __syncthreads();
    }
    int run = s[tid] - sum;
    if (base + 0 < NN) { run += v0; rp1[base + 0] = run; }
    if (base + 1 < NN) { run += v1; rp1[base + 1] = run; }
    if (base + 2 < NN) { run += v2; rp1[base + 2] = run; }
    if (base + 3 < NN) { run += v3; rp1[base + 3] = run; }
    if (tid == 255) bsum[blockIdx.x] = s[255];
}

__global__ void k_scan2(int* bsum, int nb) {  // exclusive scan in-place, nb<=128
    __shared__ int s[128];
    int tid = threadIdx.x;
    int v = (tid < nb) ? bsum[tid] : 0;
    s[tid] = v; __syncthreads();
    for (int off = 1; off < 128; off <<= 1) {
        int t = (tid >= off) ? s[tid - off] : 0;
        __syncthreads(); s[tid] += t; __syncthreads();
    }
    if (tid < nb) bsum[tid] = s[tid] - v;
}

__global__ void k_scan3(int* rowptr, const int* bsum) {
    int tid = threadIdx.x;
    int base = blockIdx.x * 1024 + tid * 4;
    int add = bsum[blockIdx.x];
    #pragma unroll
    for (int i = 0; i < 4; i++) {
        int idx = base + i;
        if (idx < NN) rowptr[idx + 1] += add;
    }
    if (blockIdx.x == 0 && tid == 0) rowptr[0] = 0;
}

// self-loop goes in slot rowptr[c]; cursor starts after it
__global__ void k_self(const int* rowptr, const int* deg, int* rows, float2* ab, int* cursor) {
    int i = blockIdx.x * 256 + threadIdx.x;
    if (i < NN) {
        int p = rowptr[i];
        rows[p] = i;
        ab[p] = make_float2(1.0f / (float)deg[i], 1.0f);  // dis[c]^2 ; einv(1.0)=1
        cursor[i] = p + 1;
    }
}

__global__ void k_fill(const int* er, const int* ec, const float* ew, const int* deg,
                       int* cursor, int* rows, float2* ab) {
    int e = blockIdx.x * 256 + threadIdx.x;
    if (e < NE) {
        int r = er[e], c = ec[e];
        int p = atomicAdd(&cursor[c], 1);
        rows[p] = r;
        float dn = rsqrtf((float)deg[r] * (float)deg[c]);   // dis[r]*dis[c]
        float bb = fminf(rsqrtf(ew[e]), 1.0f);              // clamped ew^-0.5
        ab[p] = make_float2(dn, bb);
    }
}

// ---------- packing ----------
// Xc[N][256] bf16 = [x | d2an | 0-pad]
__global__ void k_packx(const float* x, const float* d2, unsigned short* Xc) {
    int idx = blockIdx.x * 256 + threadIdx.x;
    if (idx < NN * 256) {
        int r = idx >> 8, k = idx & 255;
        float v = 0.f;
        if (k < 128) v = x[r * 128 + k];
        else if (k < 226) v = d2[r * 98 + (k - 128)];
        Xc[idx] = f2bf(v);
    }
}

// Weight pre-packed in MFMA B-fragment order: Wf[ks][ct][lane][j] holds
// Worig[c][k] with k = ks*32 + (lane>>4)*8 + j, c = ct*16 + (lane&15).
__global__ void k_packwnode(const float* w1, const float* w2, unsigned short* Wf) {
    int idx = blockIdx.x * 256 + threadIdx.x;   // 8*16*64*8 = 65536
    if (idx < 65536) {
        int j = idx & 7, lane = (idx >> 3) & 63, ct = (idx >> 9) & 15, ks = idx >> 13;
        int k = ks * 32 + (lane >> 4) * 8 + j;
        int c = ct * 16 + (lane & 15);
        float v = 0.f;
        if (k < 226) v = (c < 128) ? w1[c * 226 + k] : w2[(c - 128) * 226 + k];
        Wf[idx] = f2bf(v);
    }
}

__global__ void k_packwl(const float* wa, const float* wb, unsigned short* Wf) {
    int idx = blockIdx.x * 256 + threadIdx.x;   // 8*8*64*8 = 32768
    if (idx < 32768) {
        int j = idx & 7, lane = (idx >> 3) & 63, ct = (idx >> 9) & 7, ks = idx >> 12;
        int k = ks * 32 + (lane >> 4) * 8 + j;
        int c = ct * 16 + (lane & 15);
        float v = (k < 128) ? wa[c * 128 + k] : wb[c * 128 + (k - 128)];
        Wf[idx] = f2bf(v);
    }
}

// ---------- aggregation: one wave per node ----------
// g1[c] = sum a_e * S[row_e], g2[c] = sum b_e * S[row_e]; G[c] = [g1|g2] bf16
__global__ __launch_bounds__(256) void k_agg(const unsigned short* S, int srst, int soff,
                                             const int* rowptr, const int* rows,
                                             const float2* ab, unsigned short* G) {
    int c = blockIdx.x * 4 + (threadIdx.x >> 6);
    int lane = threadIdx.x & 63;
    if (c >= NN) return;
    float a0 = 0.f, a1 = 0.f, b0 = 0.f, b1 = 0.f;
    int jb = rowptr[c], je = rowptr[c + 1];
    for (int j = jb; j < je; j++) {
        int r = rows[j];
        float2 w = ab[j];
        unsigned int u = *(const unsigned int*)(S + (size_t)r * srst + soff + lane * 2);
        float x0 = bf2f((unsigned short)(u & 0xFFFF));
        float x1 = bf2f((unsigned short)(u >> 16));
        a0 += w.x * x0; a1 += w.x * x1;
        b0 += w.y * x0; b1 += w.y * x1;
    }
    unsigned int* gd = (unsigned int*)(G + (size_t)c * 256);
    gd[lane]      = (unsigned int)f2bf(a0) | ((unsigned int)f2bf(a1) << 16);
    gd[64 + lane] = (unsigned int)f2bf(b0) | ((unsigned int)f2bf(b1) << 16);
}

// ---------- GEMM: C[64 x 128-per-blockIdx.y] = A[N][256] @ Wf, no LDS ----------
// MODE 0: store bf16 plain; 1: store bf16 0.5*relu(T)+0.5*relu(acc); 2: same but f32 to out
template <int MODE>
__global__ __launch_bounds__(256) void k_gemm(const unsigned short* A, int arst,
                                              const unsigned short* Wf, int nct_total,
                                              unsigned short* outB, float* outF,
                                              const unsigned short* T, int orst) {
    int wave = threadIdx.x >> 6, lane = threadIdx.x & 63;
    int m = lane & 15, quad = lane >> 4;
    int row0 = blockIdx.x * 64 + wave * 16;
    int arow = row0 + m;
    bool rowok = arow < NN;
    const unsigned short* Ap = A + (size_t)arow * arst + quad * 8;
    int ctbase = blockIdx.y * 8;
    f32x4 acc[8];
    #pragma unroll
    for (int t = 0; t < 8; t++) acc[t] = (f32x4){0.f, 0.f, 0.f, 0.f};

    #pragma unroll
    for (int ks = 0; ks < 8; ks++) {
        bf16x8 a;
        if (rowok) a = *(const bf16x8*)(Ap + ks * 32);
        else       a = (bf16x8){0, 0, 0, 0, 0, 0, 0, 0};
        const unsigned short* wp = Wf + ((size_t)(ks * nct_total + ctbase) * 64 + lane) * 8;
        #pragma unroll
        for (int t = 0; t < 8; t++) {
            bf16x8 b = *(const bf16x8*)(wp + t * 512);
            acc[t] = __builtin_amdgcn_mfma_f32_16x16x32_bf16(a, b, acc[t], 0, 0, 0);
        }
    }

    int col0 = blockIdx.y * 128;
    #pragma unroll
    for (int t = 0; t < 8; t++) {
        int c = col0 + t * 16 + m;
        #pragma unroll
        for (int rg = 0; rg < 4; rg++) {
            int r = row0 + quad * 4 + rg;
            if (r < NN) {
                float v = acc[t][rg];
                if (MODE == 0) {
                    outB[(size_t)r * orst + c] = f2bf(v);
                } else {
                    float tv = bf2f(T[(size_t)r * 128 + c]);
                    float o = 0.5f * fmaxf(tv, 0.f) + 0.5f * fmaxf(v, 0.f);
                    if (MODE == 1) outB[(size_t)r * orst + c] = f2bf(o);
                    else           outF[(size_t)r * 128 + c] = o;
                }
            }
        }
    }
}

extern "C" void kernel_launch(void* const* d_in, const int* in_sizes, int n_in,
                              void* d_out, int out_size, void* d_ws, size_t ws_size,
                              hipStream_t stream) {
    const float* x      = (const float*)d_in[0];
    const float* d2an   = (const float*)d_in[1];
    const int*   ei0    = (const int*)d_in[2];
    const float* ew0    = (const float*)d_in[3];
    const int*   ei1    = (const int*)d_in[4];
    const float* ew1    = (const float*)d_in[5];
    const float* nodeW1 = (const float*)d_in[6];
    const float* nodeW2 = (const float*)d_in[7];
    const float* W1a = (const float*)d_in[8],  *W1b = (const float*)d_in[9];
    const float* W2a = (const float*)d_in[10], *W2b = (const float*)d_in[11];
    const float* W3a = (const float*)d_in[12], *W3b = (const float*)d_in[13];
    const float* W4a = (const float*)d_in[14], *W4b = (const float*)d_in[15];
    float* out = (float*)d_out;

    // ws carve-out (~171 MB total)
    char* p = (char*)d_ws;
    auto alloc = [&](size_t bytes) -> char* {
        char* r = p; p += (bytes + 255) & ~(size_t)255; return r;
    };
    unsigned short* bufA   = (unsigned short*)alloc((size_t)NN * 256 * 2); // Xc -> G
    unsigned short* bufB   = (unsigned short*)alloc((size_t)NN * 256 * 2); // P  -> XM
    unsigned short* Tbuf   = (unsigned short*)alloc((size_t)NN * 128 * 2);
    unsigned short* Wfnode = (unsigned short*)alloc(65536 * 2);
    unsigned short* WfL0   = (unsigned short*)alloc(32768 * 2);
    unsigned short* WfL1   = (unsigned short*)alloc(32768 * 2);
    unsigned short* WfL2   = (unsigned short*)alloc(32768 * 2);
    unsigned short* WfL3   = (unsigned short*)alloc(32768 * 2);
    int*    deg0    = (int*)alloc((size_t)NN * 4);
    int*    deg1    = (int*)alloc((size_t)NN * 4);
    int*    rowptr0 = (int*)alloc((size_t)(NN + 1) * 4);
    int*    rowptr1 = (int*)alloc((size_t)(NN + 1) * 4);
    int*    cursor  = (int*)alloc((size_t)NN * 4);
    int*    bsum    = (int*)alloc(512);
    int*    rows0   = (int*)alloc((size_t)ETOT * 4);
    float2* ab0     = (float2*)alloc((size_t)ETOT * 8);
    int*    rows1   = (int*)alloc((size_t)ETOT * 4);
    float2* ab1     = (float2*)alloc((size_t)ETOT * 8);

    int nbN  = (NN + 255) / 256;
    int nbE  = (NE + 255) / 256;
    int nbS  = (NN + 1023) / 1024;        // 98 scan blocks
    dim3 gP((NN + 63) / 64, 2);           // P gemm: 256 output cols
    dim3 gL((NN + 63) / 64, 1);           // layer gemms: 128 output cols
    int nbA = (NN + 3) / 4;               // agg: 4 waves/block, 1 wave/node

    // --- CSR build (per edge set) ---
    k_init_deg<<<nbN, 256, 0, stream>>>(deg0, deg1);
    k_count<<<nbE, 256, 0, stream>>>(ei0 + NE, deg0);
    k_count<<<nbE, 256, 0, stream>>>(ei1 + NE, deg1);
    k_scan1<<<nbS, 256, 0, stream>>>(deg0, rowptr0 + 1, bsum);
    k_scan2<<<1, 128, 0, stream>>>(bsum, nbS);
    k_scan3<<<nbS, 256, 0, stream>>>(rowptr0, bsum);
    k_scan1<<<nbS, 256, 0, stream>>>(deg1, rowptr1 + 1, bsum);
    k_scan2<<<1, 128, 0, stream>>>(bsum, nbS);
    k_scan3<<<nbS, 256, 0, stream>>>(rowptr1, bsum);
    k_self<<<nbN, 256, 0, stream>>>(rowptr0, deg0, rows0, ab0, cursor);
    k_fill<<<nbE, 256, 0, stream>>>(ei0, ei0 + NE, ew0, deg0, cursor, rows0, ab0);
    k_self<<<nbN, 256, 0, stream>>>(rowptr1, deg1, rows1, ab1, cursor);
    k_fill<<<nbE, 256, 0, stream>>>(ei1, ei1 + NE, ew1, deg1, cursor, rows1, ab1);

    // --- packing ---
    k_packx<<<NN, 256, 0, stream>>>(x, d2an, bufA);
    k_packwnode<<<256, 256, 0, stream>>>(nodeW1, nodeW2, Wfnode);
    k_packwl<<<128, 256, 0, stream>>>(W1a, W1b, WfL0);
    k_packwl<<<128, 256, 0, stream>>>(W2a, W2b, WfL1);
    k_packwl<<<128, 256, 0, stream>>>(W3a, W3b, WfL2);
    k_packwl<<<128, 256, 0, stream>>>(W4a, W4b, WfL3);

    // --- round 1: P = [x|d2an] @ [nodeW1|nodeW2]^T  (bufA=Xc -> bufB=P) ---
    k_gemm<0><<<gP, 256, 0, stream>>>(bufA, 256, Wfnode, 16, bufB, nullptr, nullptr, 256);
    // layer0 (set0 on x0p): agg -> G(bufA); T = g1@W1a^T+g2@W1b^T
    k_agg<<<nbA, 256, 0, stream>>>(bufB, 256, 0, rowptr0, rows0, ab0, bufA);
    k_gemm<0><<<gL, 256, 0, stream>>>(bufA, 256, WfL0, 8, Tbuf, nullptr, nullptr, 128);
    // layer1 (set1 on x1p): agg -> G(bufA); XM = 0.5relu(T)+0.5relu(g@W2) -> bufB
    k_agg<<<nbA, 256, 0, stream>>>(bufB, 256, 128, rowptr1, rows1, ab1, bufA);
    k_gemm<1><<<gL, 256, 0, stream>>>(bufA, 256, WfL1, 8, bufB, nullptr, Tbuf, 128);

    // --- round 2 on XM (bufB, stride 128) ---
    k_agg<<<nbA, 256, 0, stream>>>(bufB, 128, 0, rowptr0, rows0, ab0, bufA);
    k_gemm<0><<<gL, 256, 0, stream>>>(bufA, 256, WfL2, 8, Tbuf, nullptr, nullptr, 128);
    k_agg<<<nbA, 256, 0, stream>>>(bufB, 128, 0, rowptr1, rows1, ab1, bufA);
    k_gemm<2><<<gL, 256, 0, stream>>>(bufA, 256, WfL3, 8, nullptr, out, Tbuf, 128);
}

// Round 2
// 997.469 us; speedup vs baseline: 1.4520x; 1.4520x over previous
//
#include <hip/hip_runtime.h>
#include <hip/hip_fp16.h>
#include <stdint.h>

// Problem constants (from reference)
#define NN 100000      // nodes
#define NE 1600000     // edges per set
#define ETOT (NE + NN) // edges + self loops

typedef __attribute__((ext_vector_type(8))) short bf16x8;
typedef __attribute__((ext_vector_type(4))) float f32x4;
typedef __attribute__((ext_vector_type(4))) unsigned short us4;

__device__ __forceinline__ float bf2f(unsigned short u) {
    union { unsigned int i; float f; } x; x.i = ((unsigned int)u) << 16; return x.f;
}
__device__ __forceinline__ unsigned short f2bf(float f) {
    union { float f; unsigned int i; } x; x.f = f;
    unsigned int i = x.i;
    return (unsigned short)((i + 0x7FFFu + ((i >> 16) & 1u)) >> 16);
}
// pack two fp16 coefficients into one int
__device__ __forceinline__ int packab(float a, float b) {
    unsigned int ua = __half_as_ushort(__float2half_rn(a));
    unsigned int ub = __half_as_ushort(__float2half_rn(b));
    return (int)(ua | (ub << 16));
}
__device__ __forceinline__ float2 unpackab(int p) {
    float a = __half2float(__ushort_as_half((unsigned short)(p & 0xFFFF)));
    float b = __half2float(__ushort_as_half((unsigned short)(((unsigned int)p) >> 16)));
    return make_float2(a, b);
}

// ---------- CSR build ----------
__global__ void k_init_deg(int* deg0, int* deg1) {
    int i = blockIdx.x * 256 + threadIdx.x;
    if (i < NN) { deg0[i] = 1; deg1[i] = 1; }   // self-loop included
}

__global__ void k_count(const int* col, int* deg) {
    int e = blockIdx.x * 256 + threadIdx.x;
    if (e < NE) atomicAdd(&deg[col[e]], 1);
}

// block scans 1024 elems (4/thread); writes inclusive scan into rowptr[i+1]
__global__ void k_scan1(const int* deg, int* rp1, int* bsum) {
    __shared__ int s[256];
    int tid = threadIdx.x;
    int base = blockIdx.x * 1024 + tid * 4;
    int v0 = 0, v1 = 0, v2 = 0, v3 = 0;
    if (base + 0 < NN) v0 = deg[base + 0];
    if (base + 1 < NN) v1 = deg[base + 1];
    if (base + 2 < NN) v2 = deg[base + 2];
    if (base + 3 < NN) v3 = deg[base + 3];
    int sum = v0 + v1 + v2 + v3;
    s[tid] = sum; __syncthreads();
    for (int off = 1; off < 256; off <<= 1) {
        int t = (tid >= off) ? s[tid - off] : 0;
        __syncthreads(); s[tid] += t; __syncthreads();
    }
    int run = s[tid] - sum;
    if (base + 0 < NN) { run += v0; rp1[base + 0] = run; }
    if (base + 1 < NN) { run += v1; rp1[base + 1] = run; }
    if (base + 2 < NN) { run += v2; rp1[base + 2] = run; }
    if (base + 3 < NN) { run += v3; rp1[base + 3] = run; }
    if (tid == 255) bsum[blockIdx.x] = s[255];
}

__global__ void k_scan2(int* bsum, int nb) {  // exclusive scan in-place, nb<=128
    __shared__ int s[128];
    int tid = threadIdx.x;
    int v = (tid < nb) ? bsum[tid] : 0;
    s[tid] = v; __syncthreads();
    for (int off = 1; off < 128; off <<= 1) {
        int t = (tid >= off) ? s[tid - off] : 0;
        __syncthreads(); s[tid] += t; __syncthreads();
    }
    if (tid < nb) bsum[tid] = s[tid] - v;
}

__global__ void k_scan3(int* rowptr, const int* bsum) {
    int tid = threadIdx.x;
    int base = blockIdx.x * 1024 + tid * 4;
    int add = bsum[blockIdx.x];
    #pragma unroll
    for (int i = 0; i < 4; i++) {
        int idx = base + i;
        if (idx < NN) rowptr[idx + 1] += add;
    }
    if (blockIdx.x == 0 && tid == 0) rowptr[0] = 0;
}

// self-loop goes in slot rowptr[c]; cursor starts after it
__global__ void k_self(const int* rowptr, const int* deg, int2* edges, int* cursor) {
    int i = blockIdx.x * 256 + threadIdx.x;
    if (i < NN) {
        int p = rowptr[i];
        edges[p] = make_int2(i, packab(1.0f / (float)deg[i], 1.0f));
        cursor[i] = p + 1;
    }
}

__global__ void k_fill(const int* er, const int* ec, const float* ew, const int* deg,
                       int* cursor, int2* edges) {
    int e = blockIdx.x * 256 + threadIdx.x;
    if (e < NE) {
        int r = er[e], c = ec[e];
        int p = atomicAdd(&cursor[c], 1);
        float dn = rsqrtf((float)deg[r] * (float)deg[c]);   // dis[r]*dis[c]
        float bb = fminf(rsqrtf(ew[e]), 1.0f);              // clamped ew^-0.5
        edges[p] = make_int2(r, packab(dn, bb));
    }
}

// ---------- packing ----------
// Xc[N][256] bf16 = [x | d2an | 0-pad]; 4 cols/thread
__global__ void k_packx(const float* x, const float* d2, unsigned short* Xc) {
    int idx = blockIdx.x * 256 + threadIdx.x;   // NN*64 total
    if (idx >= NN * 64) return;
    int r = idx >> 6, k4 = (idx & 63) << 2;
    us4 o;
    if (k4 < 128) {
        float4 v = *(const float4*)(x + (size_t)r * 128 + k4);
        o[0] = f2bf(v.x); o[1] = f2bf(v.y); o[2] = f2bf(v.z); o[3] = f2bf(v.w);
    } else {
        #pragma unroll
        for (int i = 0; i < 4; i++) {
            int k = k4 + i;
            float v = (k < 226) ? d2[(size_t)r * 98 + (k - 128)] : 0.f;
            o[i] = f2bf(v);
        }
    }
    *(us4*)(Xc + (size_t)r * 256 + k4) = o;
}

// All weights packed in one dispatch, MFMA B-fragment order:
// Wf[ks][ct][lane][j] = Worig[c][k], k = ks*32 + (lane>>4)*8 + j, c = ct*16 + (lane&15)
__global__ void k_packw(const float* wn1, const float* wn2,
                        const float* w1a, const float* w1b,
                        const float* w2a, const float* w2b,
                        const float* w3a, const float* w3b,
                        const float* w4a, const float* w4b,
                        unsigned short* Wfnode, unsigned short* WfL) {
    int idx = blockIdx.x * 256 + threadIdx.x;   // 65536 + 4*32768 = 196608
    if (idx < 65536) {
        int j = idx & 7, lane = (idx >> 3) & 63, ct = (idx >> 9) & 15, ks = idx >> 13;
        int k = ks * 32 + (lane >> 4) * 8 + j;
        int c = ct * 16 + (lane & 15);
        float v = 0.f;
        if (k < 226) v = (c < 128) ? wn1[c * 226 + k] : wn2[(c - 128) * 226 + k];
        Wfnode[idx] = f2bf(v);
    } else if (idx < 196608) {
        int li = idx - 65536;
        int set = li >> 15, r = li & 32767;
        const float* wa = (set == 0) ? w1a : (set == 1) ? w2a : (set == 2) ? w3a : w4a;
        const float* wb = (set == 0) ? w1b : (set == 1) ? w2b : (set == 2) ? w3b : w4b;
        int j = r & 7, lane = (r >> 3) & 63, ct = (r >> 9) & 7, ks = r >> 12;
        int k = ks * 32 + (lane >> 4) * 8 + j;
        int c = ct * 16 + (lane & 15);
        float v = (k < 128) ? wa[c * 128 + k] : wb[c * 128 + (k - 128)];
        WfL[li] = f2bf(v);
    }
}

// ---------- aggregation: one wave per node, 4-way unrolled for MLP ----------
// g1[c] = sum a_e * S[row_e], g2[c] = sum b_e * S[row_e]; G[c] = [g1|g2] bf16
__global__ __launch_bounds__(256) void k_agg(const unsigned short* S, int srst, int soff,
                                             const int* rowptr, const int2* edges,
                                             unsigned short* G) {
    int c = blockIdx.x * 4 + (threadIdx.x >> 6);
    int lane = threadIdx.x & 63;
    if (c >= NN) return;
    float a0 = 0.f, a1 = 0.f, b0 = 0.f, b1 = 0.f;
    int jb = rowptr[c], je = rowptr[c + 1];
    const unsigned short* Sb = S + soff + lane * 2;
    int j = jb;
    for (; j + 4 <= je; j += 4) {
        int2 e0 = edges[j + 0];
        int2 e1 = edges[j + 1];
        int2 e2 = edges[j + 2];
        int2 e3 = edges[j + 3];
        unsigned int u0 = *(const unsigned int*)(Sb + (size_t)e0.x * srst);
        unsigned int u1 = *(const unsigned int*)(Sb + (size_t)e1.x * srst);
        unsigned int u2 = *(const unsigned int*)(Sb + (size_t)e2.x * srst);
        unsigned int u3 = *(const unsigned int*)(Sb + (size_t)e3.x * srst);
        float2 w0 = unpackab(e0.y), w1 = unpackab(e1.y);
        float2 w2 = unpackab(e2.y), w3 = unpackab(e3.y);
        float x00 = bf2f((unsigned short)(u0 & 0xFFFF)), x01 = bf2f((unsigned short)(u0 >> 16));
        float x10 = bf2f((unsigned short)(u1 & 0xFFFF)), x11 = bf2f((unsigned short)(u1 >> 16));
        float x20 = bf2f((unsigned short)(u2 & 0xFFFF)), x21 = bf2f((unsigned short)(u2 >> 16));
        float x30 = bf2f((unsigned short)(u3 & 0xFFFF)), x31 = bf2f((unsigned short)(u3 >> 16));
        a0 += w0.x * x00; a1 += w0.x * x01; b0 += w0.y * x00; b1 += w0.y * x01;
        a0 += w1.x * x10; a1 += w1.x * x11; b0 += w1.y * x10; b1 += w1.y * x11;
        a0 += w2.x * x20; a1 += w2.x * x21; b0 += w2.y * x20; b1 += w2.y * x21;
        a0 += w3.x * x30; a1 += w3.x * x31; b0 += w3.y * x30; b1 += w3.y * x31;
    }
    for (; j < je; j++) {
        int2 e = edges[j];
        unsigned int u = *(const unsigned int*)(Sb + (size_t)e.x * srst);
        float2 w = unpackab(e.y);
        float x0 = bf2f((unsigned short)(u & 0xFFFF)), x1 = bf2f((unsigned short)(u >> 16));
        a0 += w.x * x0; a1 += w.x * x1; b0 += w.y * x0; b1 += w.y * x1;
    }
    unsigned int* gd = (unsigned int*)(G + (size_t)c * 256);
    gd[lane]      = (unsigned int)f2bf(a0) | ((unsigned int)f2bf(a1) << 16);
    gd[64 + lane] = (unsigned int)f2bf(b0) | ((unsigned int)f2bf(b1) << 16);
}

// ---------- GEMM: C[64 x 128-per-blockIdx.y] = A[N][256] @ Wf, no LDS ----------
// MODE 0: store bf16 plain; 1: store bf16 0.5*relu(T)+0.5*relu(acc); 2: same but f32 to out
template <int MODE>
__global__ __launch_bounds__(256) void k_gemm(const unsigned short* A, int arst,
                                              const unsigned short* Wf, int nct_total,
                                              unsigned short* outB, float* outF,
                                              const unsigned short* T, int orst) {
    int wave = threadIdx.x >> 6, lane = threadIdx.x & 63;
    int m = lane & 15, quad = lane >> 4;
    int row0 = blockIdx.x * 64 + wave * 16;
    int arow = row0 + m;
    bool rowok = arow < NN;
    const unsigned short* Ap = A + (size_t)arow * arst + quad * 8;
    int ctbase = blockIdx.y * 8;
    f32x4 acc[8];
    #pragma unroll
    for (int t = 0; t < 8; t++) acc[t] = (f32x4){0.f, 0.f, 0.f, 0.f};

    #pragma unroll
    for (int ks = 0; ks < 8; ks++) {
        bf16x8 a;
        if (rowok) a = *(const bf16x8*)(Ap + ks * 32);
        else       a = (bf16x8){0, 0, 0, 0, 0, 0, 0, 0};
        const unsigned short* wp = Wf + ((size_t)(ks * nct_total + ctbase) * 64 + lane) * 8;
        #pragma unroll
        for (int t = 0; t < 8; t++) {
            bf16x8 b = *(const bf16x8*)(wp + t * 512);
            acc[t] = __builtin_amdgcn_mfma_f32_16x16x32_bf16(a, b, acc[t], 0, 0, 0);
        }
    }

    int col0 = blockIdx.y * 128;
    #pragma unroll
    for (int t = 0; t < 8; t++) {
        int c = col0 + t * 16 + m;
        #pragma unroll
        for (int rg = 0; rg < 4; rg++) {
            int r = row0 + quad * 4 + rg;
            if (r < NN) {
                float v = acc[t][rg];
                if (MODE == 0) {
                    outB[(size_t)r * orst + c] = f2bf(v);
                } else {
                    float tv = bf2f(T[(size_t)r * 128 + c]);
                    float o = 0.5f * fmaxf(tv, 0.f) + 0.5f * fmaxf(v, 0.f);
                    if (MODE == 1) outB[(size_t)r * orst + c] = f2bf(o);
                    else           outF[(size_t)r * 128 + c] = o;
                }
            }
        }
    }
}

extern "C" void kernel_launch(void* const* d_in, const int* in_sizes, int n_in,
                              void* d_out, int out_size, void* d_ws, size_t ws_size,
                              hipStream_t stream) {
    const float* x      = (const float*)d_in[0];
    const float* d2an   = (const float*)d_in[1];
    const int*   ei0    = (const int*)d_in[2];
    const float* ew0    = (const float*)d_in[3];
    const int*   ei1    = (const int*)d_in[4];
    const float* ew1    = (const float*)d_in[5];
    const float* nodeW1 = (const float*)d_in[6];
    const float* nodeW2 = (const float*)d_in[7];
    const float* W1a = (const float*)d_in[8],  *W1b = (const float*)d_in[9];
    const float* W2a = (const float*)d_in[10], *W2b = (const float*)d_in[11];
    const float* W3a = (const float*)d_in[12], *W3b = (const float*)d_in[13];
    const float* W4a = (const float*)d_in[14], *W4b = (const float*)d_in[15];
    float* out = (float*)d_out;

    // ws carve-out
    char* p = (char*)d_ws;
    auto alloc = [&](size_t bytes) -> char* {
        char* r = p; p += (bytes + 255) & ~(size_t)255; return r;
    };
    unsigned short* bufA   = (unsigned short*)alloc((size_t)NN * 256 * 2); // Xc -> G
    unsigned short* bufB   = (unsigned short*)alloc((size_t)NN * 256 * 2); // P  -> XM
    unsigned short* Tbuf   = (unsigned short*)alloc((size_t)NN * 128 * 2);
    unsigned short* Wfnode = (unsigned short*)alloc(65536 * 2);
    unsigned short* WfL    = (unsigned short*)alloc((size_t)4 * 32768 * 2);
    int*    deg0    = (int*)alloc((size_t)NN * 4);
    int*    deg1    = (int*)alloc((size_t)NN * 4);
    int*    rowptr0 = (int*)alloc((size_t)(NN + 1) * 4);
    int*    rowptr1 = (int*)alloc((size_t)(NN + 1) * 4);
    int*    cursor  = (int*)alloc((size_t)NN * 4);
    int*    bsum    = (int*)alloc(512);
    int2*   edges0  = (int2*)alloc((size_t)ETOT * 8);
    int2*   edges1  = (int2*)alloc((size_t)ETOT * 8);

    int nbN  = (NN + 255) / 256;
    int nbE  = (NE + 255) / 256;
    int nbS  = (NN + 1023) / 1024;        // 98 scan blocks
    dim3 gP((NN + 63) / 64, 2);           // P gemm: 256 output cols
    dim3 gL((NN + 63) / 64, 1);           // layer gemms: 128 output cols
    int nbA = (NN + 3) / 4;               // agg: 4 waves/block, 1 wave/node

    // --- CSR build (per edge set) ---
    k_init_deg<<<nbN, 256, 0, stream>>>(deg0, deg1);
    k_count<<<nbE, 256, 0, stream>>>(ei0 + NE, deg0);
    k_count<<<nbE, 256, 0, stream>>>(ei1 + NE, deg1);
    k_scan1<<<nbS, 256, 0, stream>>>(deg0, rowptr0 + 1, bsum);
    k_scan2<<<1, 128, 0, stream>>>(bsum, nbS);
    k_scan3<<<nbS, 256, 0, stream>>>(rowptr0, bsum);
    k_scan1<<<nbS, 256, 0, stream>>>(deg1, rowptr1 + 1, bsum);
    k_scan2<<<1, 128, 0, stream>>>(bsum, nbS);
    k_scan3<<<nbS, 256, 0, stream>>>(rowptr1, bsum);
    k_self<<<nbN, 256, 0, stream>>>(rowptr0, deg0, edges0, cursor);
    k_fill<<<nbE, 256, 0, stream>>>(ei0, ei0 + NE, ew0, deg0, cursor, edges0);
    k_self<<<nbN, 256, 0, stream>>>(rowptr1, deg1, edges1, cursor);
    k_fill<<<nbE, 256, 0, stream>>>(ei1, ei1 + NE, ew1, deg1, cursor, edges1);

    // --- packing ---
    k_packx<<<(NN * 64 + 255) / 256, 256, 0, stream>>>(x, d2an, bufA);
    k_packw<<<768, 256, 0, stream>>>(nodeW1, nodeW2, W1a, W1b, W2a, W2b,
                                     W3a, W3b, W4a, W4b, Wfnode, WfL);

    // --- round 1: P = [x|d2an] @ [nodeW1|nodeW2]^T  (bufA=Xc -> bufB=P) ---
    k_gemm<0><<<gP, 256, 0, stream>>>(bufA, 256, Wfnode, 16, bufB, nullptr, nullptr, 256);
    // layer0 (set0 on x0p): agg -> G(bufA); T = g1@W1a^T+g2@W1b^T
    k_agg<<<nbA, 256, 0, stream>>>(bufB, 256, 0, rowptr0, edges0, bufA);
    k_gemm<0><<<gL, 256, 0, stream>>>(bufA, 256, WfL, 8, Tbuf, nullptr, nullptr, 128);
    // layer1 (set1 on x1p): agg -> G(bufA); XM = 0.5relu(T)+0.5relu(g@W2) -> bufB
    k_agg<<<nbA, 256, 0, stream>>>(bufB, 256, 128, rowptr1, edges1, bufA);
    k_gemm<1><<<gL, 256, 0, stream>>>(bufA, 256, WfL + 32768, 8, bufB, nullptr, Tbuf, 128);

    // --- round 2 on XM (bufB, stride 128) ---
    k_agg<<<nbA, 256, 0, stream>>>(bufB, 128, 0, rowptr0, edges0, bufA);
    k_gemm<0><<<gL, 256, 0, stream>>>(bufA, 256, WfL + 2 * 32768, 8, Tbuf, nullptr, nullptr, 128);
    k_agg<<<nbA, 256, 0, stream>>>(bufB, 128, 0, rowptr1, edges1, bufA);
    k_gemm<2><<<gL, 256, 0, stream>>>(bufA, 256, WfL + 3 * 32768, 8, nullptr, out, Tbuf, 128);
}